// Round 4
// baseline (582.862 us; speedup 1.0000x reference)
//
#include <hip/hip_runtime.h>

typedef __bf16 bf16x8 __attribute__((ext_vector_type(8)));
typedef float  f32x4  __attribute__((ext_vector_type(4)));

#define DEVI static __device__ __forceinline__

DEVI __bf16 tobf(float f) { return static_cast<__bf16>(f); }

// ---------------- cast fp32 -> bf16 (8 elems / thread) ----------------
__global__ __launch_bounds__(256) void cast_f32_bf16(
    const float* __restrict__ in, __bf16* __restrict__ out, int n8)
{
  int i = blockIdx.x * 256 + threadIdx.x;
  if (i >= n8) return;
  const float4* p = (const float4*)in + (size_t)i * 2;
  float4 a = p[0], b = p[1];
  bf16x8 o;
  o[0]=tobf(a.x); o[1]=tobf(a.y); o[2]=tobf(a.z); o[3]=tobf(a.w);
  o[4]=tobf(b.x); o[5]=tobf(b.y); o[6]=tobf(b.z); o[7]=tobf(b.w);
  ((bf16x8*)out)[i] = o;
}

// ---------------- transpose + cast: W[R,C] f32 -> Wt[C,R] bf16 ----------------
__global__ __launch_bounds__(256) void transpose_cast(
    const float* __restrict__ W, __bf16* __restrict__ Wt, int R, int C)
{
  __shared__ float tile[32][33];
  const int tx = threadIdx.x & 31;
  const int ty = threadIdx.x >> 5;              // 0..7
  const int c0 = blockIdx.x * 32, r0 = blockIdx.y * 32;
  #pragma unroll
  for (int i = 0; i < 4; ++i)
    tile[ty + i*8][tx] = W[(size_t)(r0 + ty + i*8) * C + c0 + tx];
  __syncthreads();
  #pragma unroll
  for (int i = 0; i < 4; ++i)
    Wt[(size_t)(c0 + ty + i*8) * R + r0 + tx] = tobf(tile[tx][ty + i*8]);
}

// ---------------- concat 3 bias vectors of length n ----------------
__global__ __launch_bounds__(256) void concat3(
    const float* __restrict__ a, const float* __restrict__ b,
    const float* __restrict__ c, float* __restrict__ out, int n)
{
  int i = blockIdx.x * 256 + threadIdx.x;
  if (i < n) out[i] = a[i];
  else if (i < 2*n) out[i] = b[i - n];
  else if (i < 3*n) out[i] = c[i - 2*n];
}

// ---------------- BT-GEMM: C[M,N] = A[M,K] @ Bt[N,K]^T (+bias, epilogue) ------
// EPI 0: bias -> bf16 out     EPI 1: bias + exact GELU -> bf16 out
// EPI 2: bias + resid(f32) -> f32 out
template<int EPI>
__global__ __launch_bounds__(256)
void gemm_bt(const __bf16* __restrict__ A, const __bf16* __restrict__ Bt,
             const float* __restrict__ bias, const float* __restrict__ resid,
             void* __restrict__ out, int M, int N, int K)
{
  __shared__ __bf16 As[128][72];
  __shared__ __bf16 Bs[128][72];
  const int tid  = threadIdx.x;
  const int lane = tid & 63;
  const int wave = tid >> 6;
  const int wm = wave >> 1, wn = wave & 1;
  const int m0 = blockIdx.x * 128, n0 = blockIdx.y * 128;
  const int lr = lane & 15, lg = lane >> 4;
  const int srow = tid >> 3, scol = (tid & 7) * 8;

  f32x4 acc[4][4];
  f32x4 zz = {0.f, 0.f, 0.f, 0.f};
  #pragma unroll
  for (int i = 0; i < 4; ++i)
    #pragma unroll
    for (int j = 0; j < 4; ++j) acc[i][j] = zz;

  for (int k0 = 0; k0 < K; k0 += 64) {
    #pragma unroll
    for (int p = 0; p < 4; ++p) {
      const int row = p * 32 + srow;
      *(bf16x8*)&As[row][scol] = *(const bf16x8*)(A  + (size_t)(m0 + row) * K + k0 + scol);
      *(bf16x8*)&Bs[row][scol] = *(const bf16x8*)(Bt + (size_t)(n0 + row) * K + k0 + scol);
    }
    __syncthreads();
    #pragma unroll
    for (int kk = 0; kk < 2; ++kk) {
      bf16x8 af[4], bfr[4];
      #pragma unroll
      for (int i = 0; i < 4; ++i) af[i]  = *(const bf16x8*)&As[wm*64 + i*16 + lr][kk*32 + lg*8];
      #pragma unroll
      for (int j = 0; j < 4; ++j) bfr[j] = *(const bf16x8*)&Bs[wn*64 + j*16 + lr][kk*32 + lg*8];
      #pragma unroll
      for (int i = 0; i < 4; ++i)
        #pragma unroll
        for (int j = 0; j < 4; ++j)
          acc[i][j] = __builtin_amdgcn_mfma_f32_16x16x32_bf16(af[i], bfr[j], acc[i][j], 0, 0, 0);
    }
    __syncthreads();
  }

  const int orow = m0 + wm * 64;
  const int ocol = n0 + wn * 64;
  #pragma unroll
  for (int j = 0; j < 4; ++j) {
    const int col = ocol + j*16 + lr;
    const float bv = bias[col];
    #pragma unroll
    for (int i = 0; i < 4; ++i) {
      #pragma unroll
      for (int r = 0; r < 4; ++r) {
        const int row = orow + i*16 + lg*4 + r;
        const size_t o = (size_t)row * N + col;
        float v = acc[i][j][r] + bv;
        if (EPI == 0) {
          ((__bf16*)out)[o] = tobf(v);
        } else if (EPI == 1) {
          float g = 0.5f * v * (1.0f + erff(v * 0.7071067811865476f));
          ((__bf16*)out)[o] = tobf(g);
        } else {
          ((float*)out)[o] = v + resid[o];
        }
      }
    }
  }
}

// ---------------- flash attention ----------------
// QKV: [B*S, 1536] bf16 (Q|K|V each 512 = 8 heads x 64). O: [B*S, 512] bf16.
// grid: (S/64, B*H); block 256 (4 waves x 16 q-rows each).
DEVI int vt_idx(int d, int kv) {
  // swizzled VT[d][kv], row stride 72, 16B-chunk rotation by (d>>3)
  return d * 72 + ((((kv >> 3) + (d >> 3)) & 7) << 3) + (kv & 7);
}

__global__ __launch_bounds__(256)
void flash_attn(const __bf16* __restrict__ QKV, __bf16* __restrict__ O)
{
  __shared__ __bf16 Qs[64][72];
  __shared__ __bf16 Ks[64][72];
  __shared__ __bf16 VTs[64 * 72];
  __shared__ __bf16 Ps[4][16][72];

  const int tid  = threadIdx.x;
  const int lane = tid & 63;
  const int w    = tid >> 6;
  const int lr = lane & 15, lg = lane >> 4;
  const int bh = blockIdx.y;
  const int b = bh >> 3, h = bh & 7;
  const int q0 = blockIdx.x * 64;
  const size_t qkvbase = (size_t)b * 2048 * 1536 + h * 64;
  const int srow = tid >> 3, scol = (tid & 7) * 8;

  #pragma unroll
  for (int p = 0; p < 2; ++p) {
    const int row = p * 32 + srow;
    *(bf16x8*)&Qs[row][scol] = *(const bf16x8*)(QKV + qkvbase + (size_t)(q0 + row) * 1536 + scol);
  }

  float mrow[4], lrow[4];
  f32x4 oacc[4];
  f32x4 zz = {0.f, 0.f, 0.f, 0.f};
  #pragma unroll
  for (int r = 0; r < 4; ++r) { mrow[r] = -1e30f; lrow[r] = 0.f; }
  #pragma unroll
  for (int d = 0; d < 4; ++d) oacc[d] = zz;

  for (int kt = 0; kt < 32; ++kt) {
    const size_t kbase = qkvbase + 512  + (size_t)(kt * 64) * 1536;
    const size_t vbase = qkvbase + 1024 + (size_t)(kt * 64) * 1536;
    #pragma unroll
    for (int p = 0; p < 2; ++p) {
      const int row = p * 32 + srow;
      *(bf16x8*)&Ks[row][scol] = *(const bf16x8*)(QKV + kbase + (size_t)row * 1536 + scol);
      bf16x8 vv = *(const bf16x8*)(QKV + vbase + (size_t)row * 1536 + scol);
      #pragma unroll
      for (int e = 0; e < 8; ++e) VTs[vt_idx(scol + e, row)] = vv[e];
    }
    __syncthreads();

    // S = (Q K^T) * 1/8
    f32x4 sf[4];
    #pragma unroll
    for (int ct = 0; ct < 4; ++ct) {
      f32x4 s = zz;
      #pragma unroll
      for (int kk = 0; kk < 2; ++kk) {
        bf16x8 a  = *(const bf16x8*)&Qs[w*16 + lr][kk*32 + lg*8];
        bf16x8 bb = *(const bf16x8*)&Ks[ct*16 + lr][kk*32 + lg*8];
        s = __builtin_amdgcn_mfma_f32_16x16x32_bf16(a, bb, s, 0, 0, 0);
      }
      #pragma unroll
      for (int e = 0; e < 4; ++e) sf[ct][e] = s[e] * 0.125f;
    }

    // online softmax (rows r; 16-lane reduce over kv cols)
    #pragma unroll
    for (int r = 0; r < 4; ++r) {
      float tmax = fmaxf(fmaxf(sf[0][r], sf[1][r]), fmaxf(sf[2][r], sf[3][r]));
      #pragma unroll
      for (int off = 1; off < 16; off <<= 1) tmax = fmaxf(tmax, __shfl_xor(tmax, off));
      const float mnew = fmaxf(mrow[r], tmax);
      const float sc = __expf(mrow[r] - mnew);
      float psum = 0.f;
      #pragma unroll
      for (int ct = 0; ct < 4; ++ct) {
        float pv = __expf(sf[ct][r] - mnew);
        sf[ct][r] = pv;
        psum += pv;
      }
      #pragma unroll
      for (int off = 1; off < 16; off <<= 1) psum += __shfl_xor(psum, off);
      lrow[r] = lrow[r] * sc + psum;
      mrow[r] = mnew;
      #pragma unroll
      for (int d = 0; d < 4; ++d) oacc[d][r] *= sc;
    }

    // P -> LDS (per-wave buffer), C-layout element (q=lg*4+r, kv=ct*16+lr)
    #pragma unroll
    for (int ct = 0; ct < 4; ++ct)
      #pragma unroll
      for (int r = 0; r < 4; ++r)
        Ps[w][lg*4 + r][ct*16 + lr] = tobf(sf[ct][r]);

    // O += P @ V
    #pragma unroll
    for (int dt = 0; dt < 4; ++dt) {
      #pragma unroll
      for (int kk = 0; kk < 2; ++kk) {
        bf16x8 a  = *(const bf16x8*)&Ps[w][lr][kk*32 + lg*8];
        bf16x8 bb = *(const bf16x8*)&VTs[vt_idx(dt*16 + lr, kk*32 + lg*8)];
        oacc[dt] = __builtin_amdgcn_mfma_f32_16x16x32_bf16(a, bb, oacc[dt], 0, 0, 0);
      }
    }
    __syncthreads();
  }

  float linv[4];
  #pragma unroll
  for (int r = 0; r < 4; ++r) linv[r] = 1.0f / lrow[r];
  #pragma unroll
  for (int dt = 0; dt < 4; ++dt)
    #pragma unroll
    for (int r = 0; r < 4; ++r) {
      const int row = q0 + w*16 + lg*4 + r;
      O[(size_t)(b * 2048 + row) * 512 + h*64 + dt*16 + lr] = tobf(oacc[dt][r] * linv[r]);
    }
}

// ---------------- LayerNorm over D=512; writes f32 and bf16 copies -----------
__global__ __launch_bounds__(256)
void ln_kernel(const float* __restrict__ in, const float* __restrict__ gw,
               const float* __restrict__ bw, float* __restrict__ outF,
               __bf16* __restrict__ outB)
{
  const int lane = threadIdx.x & 63;
  const size_t row = (size_t)blockIdx.x * 4 + (threadIdx.x >> 6);
  const float* p = in + row * 512 + lane * 8;
  float4 v0 = *(const float4*)p;
  float4 v1 = *(const float4*)(p + 4);
  float s = (v0.x + v0.y) + (v0.z + v0.w) + (v1.x + v1.y) + (v1.z + v1.w);
  float q = v0.x*v0.x + v0.y*v0.y + v0.z*v0.z + v0.w*v0.w
          + v1.x*v1.x + v1.y*v1.y + v1.z*v1.z + v1.w*v1.w;
  #pragma unroll
  for (int off = 1; off < 64; off <<= 1) { s += __shfl_xor(s, off); q += __shfl_xor(q, off); }
  const float mean = s * (1.0f / 512.0f);
  const float var  = q * (1.0f / 512.0f) - mean * mean;
  const float rs   = rsqrtf(var + 1e-6f);
  const float4 g0 = *(const float4*)(gw + lane * 8);
  const float4 g1 = *(const float4*)(gw + lane * 8 + 4);
  const float4 b0 = *(const float4*)(bw + lane * 8);
  const float4 b1 = *(const float4*)(bw + lane * 8 + 4);
  float4 o0, o1;
  o0.x = (v0.x - mean) * rs * g0.x + b0.x;
  o0.y = (v0.y - mean) * rs * g0.y + b0.y;
  o0.z = (v0.z - mean) * rs * g0.z + b0.z;
  o0.w = (v0.w - mean) * rs * g0.w + b0.w;
  o1.x = (v1.x - mean) * rs * g1.x + b1.x;
  o1.y = (v1.y - mean) * rs * g1.y + b1.y;
  o1.z = (v1.z - mean) * rs * g1.z + b1.z;
  o1.w = (v1.w - mean) * rs * g1.w + b1.w;
  *(float4*)(outF + row * 512 + lane * 8)     = o0;
  *(float4*)(outF + row * 512 + lane * 8 + 4) = o1;
  bf16x8 ob;
  ob[0]=tobf(o0.x); ob[1]=tobf(o0.y); ob[2]=tobf(o0.z); ob[3]=tobf(o0.w);
  ob[4]=tobf(o1.x); ob[5]=tobf(o1.y); ob[6]=tobf(o1.z); ob[7]=tobf(o1.w);
  *(bf16x8*)(outB + row * 512 + lane * 8) = ob;
}

// ---------------- launch ----------------
extern "C" void kernel_launch(void* const* d_in, const int* in_sizes, int n_in,
                              void* d_out, int out_size, void* d_ws, size_t ws_size,
                              hipStream_t stream)
{
  const float* x     = (const float*)d_in[0];
  const float* t_wq  = (const float*)d_in[1];
  const float* t_bq  = (const float*)d_in[2];
  const float* t_wk  = (const float*)d_in[3];
  const float* t_bk  = (const float*)d_in[4];
  const float* t_wv  = (const float*)d_in[5];
  const float* t_bv  = (const float*)d_in[6];
  const float* t_wo  = (const float*)d_in[7];
  const float* t_bo  = (const float*)d_in[8];
  const float* s_wq  = (const float*)d_in[9];
  const float* s_bq  = (const float*)d_in[10];
  const float* s_wk  = (const float*)d_in[11];
  const float* s_bk  = (const float*)d_in[12];
  const float* s_wv  = (const float*)d_in[13];
  const float* s_bv  = (const float*)d_in[14];
  const float* s_wo  = (const float*)d_in[15];
  const float* s_bo  = (const float*)d_in[16];
  const float* ln1_g = (const float*)d_in[17];
  const float* ln1_b = (const float*)d_in[18];
  const float* ln2_g = (const float*)d_in[19];
  const float* ln2_b = (const float*)d_in[20];
  const float* f_w1  = (const float*)d_in[21];
  const float* f_b1  = (const float*)d_in[22];
  const float* f_w2  = (const float*)d_in[23];
  const float* f_b2  = (const float*)d_in[24];

  char* ws = (char*)d_ws;
  size_t off = 0;
  auto alloc = [&](size_t bytes) -> void* {
    void* p = ws + off; off += (bytes + 255) & ~(size_t)255; return p;
  };

  __bf16* qkvb  = (__bf16*)alloc(8192ull * 1536 * 2);   // 25.2 MB
  __bf16* attnb = (__bf16*)alloc(8192ull * 512 * 2);    // 8.4 MB (contiguous after qkvb)
  __bf16* gelu_b = qkvb;                                // alias: spans qkvb+attnb (33.5 MB)
  __bf16* xb    = (__bf16*)alloc(8192ull * 512 * 2);
  __bf16* h_bf  = xb;                                   // alias: xb dead after QKV1
  __bf16* wT_t  = (__bf16*)alloc(1536ull * 512 * 2);
  __bf16* wT_s  = (__bf16*)alloc(1536ull * 512 * 2);
  __bf16* woT_t = (__bf16*)alloc(512ull * 512 * 2);
  __bf16* woT_s = (__bf16*)alloc(512ull * 512 * 2);
  __bf16* w1T   = (__bf16*)alloc(2048ull * 512 * 2);
  __bf16* w2T   = (__bf16*)alloc(512ull * 2048 * 2);
  float* bcat_t = (float*)alloc(1536 * 4);
  float* bcat_s = (float*)alloc(1536 * 4);
  float* tmp_f  = (float*)alloc(8192ull * 512 * 4);
  float* h_f    = (float*)alloc(8192ull * 512 * 4);
  float* h2_f   = (float*)alloc(8192ull * 512 * 4);
  __bf16* h2_bf = (__bf16*)alloc(8192ull * 512 * 2);
  (void)in_sizes; (void)n_in; (void)out_size; (void)ws_size;

  // prepack
  cast_f32_bf16<<<2048, 256, 0, stream>>>(x, xb, 524288);
  transpose_cast<<<dim3(16,16), 256, 0, stream>>>(t_wq, wT_t,               512, 512);
  transpose_cast<<<dim3(16,16), 256, 0, stream>>>(t_wk, wT_t + 512*512,     512, 512);
  transpose_cast<<<dim3(16,16), 256, 0, stream>>>(t_wv, wT_t + 2*512*512,   512, 512);
  transpose_cast<<<dim3(16,16), 256, 0, stream>>>(s_wq, wT_s,               512, 512);
  transpose_cast<<<dim3(16,16), 256, 0, stream>>>(s_wk, wT_s + 512*512,     512, 512);
  transpose_cast<<<dim3(16,16), 256, 0, stream>>>(s_wv, wT_s + 2*512*512,   512, 512);
  transpose_cast<<<dim3(16,16), 256, 0, stream>>>(t_wo, woT_t,              512, 512);
  transpose_cast<<<dim3(16,16), 256, 0, stream>>>(s_wo, woT_s,              512, 512);
  transpose_cast<<<dim3(64,16), 256, 0, stream>>>(f_w1, w1T,                512, 2048);
  transpose_cast<<<dim3(16,64), 256, 0, stream>>>(f_w2, w2T,                2048, 512);
  concat3<<<6, 256, 0, stream>>>(t_bq, t_bk, t_bv, bcat_t, 512);
  concat3<<<6, 256, 0, stream>>>(s_bq, s_bk, s_bv, bcat_s, 512);

  // temporal attention
  gemm_bt<0><<<dim3(64,12), 256, 0, stream>>>(xb, wT_t, bcat_t, nullptr, qkvb, 8192, 1536, 512);
  flash_attn<<<dim3(32,32), 256, 0, stream>>>(qkvb, attnb);
  gemm_bt<2><<<dim3(64,4),  256, 0, stream>>>(attnb, woT_t, t_bo, x, tmp_f, 8192, 512, 512);
  ln_kernel<<<2048, 256, 0, stream>>>(tmp_f, ln1_g, ln1_b, h_f, h_bf);

  // spatial attention
  gemm_bt<0><<<dim3(64,12), 256, 0, stream>>>(h_bf, wT_s, bcat_s, nullptr, qkvb, 8192, 1536, 512);
  flash_attn<<<dim3(32,32), 256, 0, stream>>>(qkvb, attnb);
  gemm_bt<2><<<dim3(64,4),  256, 0, stream>>>(attnb, woT_s, s_bo, h_f, tmp_f, 8192, 512, 512);
  ln_kernel<<<2048, 256, 0, stream>>>(tmp_f, ln2_g, ln2_b, h2_f, h2_bf);

  // FFN
  gemm_bt<1><<<dim3(64,16), 256, 0, stream>>>(h2_bf, w1T, f_b1, nullptr, gelu_b, 8192, 2048, 512);
  gemm_bt<2><<<dim3(64,4),  256, 0, stream>>>(gelu_b, w2T, f_b2, h2_f, (float*)d_out, 8192, 512, 2048);
}

// Round 6
// 534.862 us; speedup vs baseline: 1.0897x; 1.0897x over previous
//
#include <hip/hip_runtime.h>

typedef __bf16 bf16x8 __attribute__((ext_vector_type(8)));
typedef float  f32x4  __attribute__((ext_vector_type(4)));

#define DEVI static __device__ __forceinline__

DEVI __bf16 tobf(float f) { return static_cast<__bf16>(f); }

// ---------------- cast fp32 -> bf16 (8 elems / thread) ----------------
__global__ __launch_bounds__(256) void cast_f32_bf16(
    const float* __restrict__ in, __bf16* __restrict__ out, int n8)
{
  int i = blockIdx.x * 256 + threadIdx.x;
  if (i >= n8) return;
  const float4* p = (const float4*)in + (size_t)i * 2;
  float4 a = p[0], b = p[1];
  bf16x8 o;
  o[0]=tobf(a.x); o[1]=tobf(a.y); o[2]=tobf(a.z); o[3]=tobf(a.w);
  o[4]=tobf(b.x); o[5]=tobf(b.y); o[6]=tobf(b.z); o[7]=tobf(b.w);
  ((bf16x8*)out)[i] = o;
}

// ---------------- transpose + cast: W[R,C] f32 -> Wt[C,R] bf16 ----------------
__global__ __launch_bounds__(256) void transpose_cast(
    const float* __restrict__ W, __bf16* __restrict__ Wt, int R, int C)
{
  __shared__ float tile[32][33];
  const int tx = threadIdx.x & 31;
  const int ty = threadIdx.x >> 5;              // 0..7
  const int c0 = blockIdx.x * 32, r0 = blockIdx.y * 32;
  #pragma unroll
  for (int i = 0; i < 4; ++i)
    tile[ty + i*8][tx] = W[(size_t)(r0 + ty + i*8) * C + c0 + tx];
  __syncthreads();
  #pragma unroll
  for (int i = 0; i < 4; ++i)
    Wt[(size_t)(c0 + ty + i*8) * R + r0 + tx] = tobf(tile[tx][ty + i*8]);
}

// ---------------- concat 3 bias vectors of length n ----------------
__global__ __launch_bounds__(256) void concat3(
    const float* __restrict__ a, const float* __restrict__ b,
    const float* __restrict__ c, float* __restrict__ out, int n)
{
  int i = blockIdx.x * 256 + threadIdx.x;
  if (i < n) out[i] = a[i];
  else if (i < 2*n) out[i] = b[i - n];
  else if (i < 3*n) out[i] = c[i - 2*n];
}

// ------- transpose V slice of QKV into VT[b][h][d=64][s=2048] bf16 -------
// grid: (S/64, B*H); block 256.
__global__ __launch_bounds__(256)
void transpose_v(const __bf16* __restrict__ QKV, __bf16* __restrict__ VT)
{
  __shared__ __bf16 t[64][72];
  const int tid = threadIdx.x;
  const int bh = blockIdx.y;
  const int b = bh >> 3, h = bh & 7;
  const int s0 = blockIdx.x * 64;
  const int srow = tid >> 3, scol = (tid & 7) * 8;
  #pragma unroll
  for (int p = 0; p < 2; ++p) {
    const int row = srow + p * 32;
    *(bf16x8*)&t[row][scol] =
      *(const bf16x8*)(QKV + (size_t)(b * 2048 + s0 + row) * 1536 + 1024 + h * 64 + scol);
  }
  __syncthreads();
  #pragma unroll
  for (int p = 0; p < 2; ++p) {
    const int d = srow + p * 32;
    bf16x8 v;
    #pragma unroll
    for (int e = 0; e < 8; ++e) v[e] = t[scol + e][d];
    *(bf16x8*)(VT + ((size_t)bh * 64 + d) * 2048 + s0 + scol) = v;
  }
}

// ---------------- BT-GEMM: C[M,N] = A[M,K] @ Bt[N,K]^T (+bias, epilogue) ------
// EPI 0: bias -> bf16 out     EPI 1: bias + exact GELU -> bf16 out
// EPI 2: bias + resid(f32) -> f32 out
template<int EPI>
__global__ __launch_bounds__(256)
void gemm_bt(const __bf16* __restrict__ A, const __bf16* __restrict__ Bt,
             const float* __restrict__ bias, const float* __restrict__ resid,
             void* __restrict__ out, int M, int N, int K)
{
  __shared__ __bf16 As[128][72];
  __shared__ __bf16 Bs[128][72];
  const int tid  = threadIdx.x;
  const int lane = tid & 63;
  const int wave = tid >> 6;
  const int wm = wave >> 1, wn = wave & 1;
  const int m0 = blockIdx.x * 128, n0 = blockIdx.y * 128;
  const int lr = lane & 15, lg = lane >> 4;
  const int srow = tid >> 3, scol = (tid & 7) * 8;

  f32x4 acc[4][4];
  f32x4 zz = {0.f, 0.f, 0.f, 0.f};
  #pragma unroll
  for (int i = 0; i < 4; ++i)
    #pragma unroll
    for (int j = 0; j < 4; ++j) acc[i][j] = zz;

  for (int k0 = 0; k0 < K; k0 += 64) {
    #pragma unroll
    for (int p = 0; p < 4; ++p) {
      const int row = p * 32 + srow;
      *(bf16x8*)&As[row][scol] = *(const bf16x8*)(A  + (size_t)(m0 + row) * K + k0 + scol);
      *(bf16x8*)&Bs[row][scol] = *(const bf16x8*)(Bt + (size_t)(n0 + row) * K + k0 + scol);
    }
    __syncthreads();
    #pragma unroll
    for (int kk = 0; kk < 2; ++kk) {
      bf16x8 af[4], bfr[4];
      #pragma unroll
      for (int i = 0; i < 4; ++i) af[i]  = *(const bf16x8*)&As[wm*64 + i*16 + lr][kk*32 + lg*8];
      #pragma unroll
      for (int j = 0; j < 4; ++j) bfr[j] = *(const bf16x8*)&Bs[wn*64 + j*16 + lr][kk*32 + lg*8];
      #pragma unroll
      for (int i = 0; i < 4; ++i)
        #pragma unroll
        for (int j = 0; j < 4; ++j)
          acc[i][j] = __builtin_amdgcn_mfma_f32_16x16x32_bf16(af[i], bfr[j], acc[i][j], 0, 0, 0);
    }
    __syncthreads();
  }

  const int orow = m0 + wm * 64;
  const int ocol = n0 + wn * 64;
  #pragma unroll
  for (int j = 0; j < 4; ++j) {
    const int col = ocol + j*16 + lr;
    const float bv = bias[col];
    #pragma unroll
    for (int i = 0; i < 4; ++i) {
      #pragma unroll
      for (int r = 0; r < 4; ++r) {
        const int row = orow + i*16 + lg*4 + r;
        const size_t o = (size_t)row * N + col;
        float v = acc[i][j][r] + bv;
        if (EPI == 0) {
          ((__bf16*)out)[o] = tobf(v);
        } else if (EPI == 1) {
          float g = 0.5f * v * (1.0f + erff(v * 0.7071067811865476f));
          ((__bf16*)out)[o] = tobf(g);
        } else {
          ((float*)out)[o] = v + resid[o];
        }
      }
    }
  }
}

// ---------------- flash attention v2 ----------------
// QKV: [B*S, 1536] bf16 (Q|K|V each 512 = 8 heads x 64).
// VT:  [B*H][64][2048] bf16 (V transposed per head).
// O:   [B*S, 512] bf16.
// grid: (S/64, B*H); block 256 (4 waves x 16 q-rows each).
// LDS: Ks/VTs/Ps, 64-elem (128 B) rows with XOR chunk swizzle:
//   byte(row, colByte) = row*128 + (colByte ^ ((row&7)<<4))
DEVI int sw_off(int row, int colByte) {
  return row * 128 + (colByte ^ ((row & 7) << 4));
}

__global__ __launch_bounds__(256)
void flash_attn(const __bf16* __restrict__ QKV, const __bf16* __restrict__ VT,
                __bf16* __restrict__ O)
{
  __shared__ __align__(16) char Ks [64 * 128];
  __shared__ __align__(16) char VTs[64 * 128];
  __shared__ __align__(16) char Ps [4 * 16 * 128];

  const int tid  = threadIdx.x;
  const int lane = tid & 63;
  const int w    = tid >> 6;
  const int lr = lane & 15, lg = lane >> 4;
  const int bh = blockIdx.y;
  const int b = bh >> 3, h = bh & 7;
  const int q0 = blockIdx.x * 64;
  const size_t qkvbase = (size_t)b * 2048 * 1536 + h * 64;
  const size_t vtbase  = (size_t)bh * 64 * 2048;
  const int srow = tid >> 3, scol = (tid & 7) * 8;

  // Q fragments straight from global (one-time), pre-scaled by 1/sqrt(64)=0.125
  bf16x8 aq[2];
  #pragma unroll
  for (int kk = 0; kk < 2; ++kk) {
    bf16x8 t = *(const bf16x8*)(QKV + qkvbase +
                 (size_t)(q0 + w*16 + lr) * 1536 + kk*32 + lg*8);
    #pragma unroll
    for (int e = 0; e < 8; ++e) t[e] = tobf(0.125f * (float)t[e]);
    aq[kk] = t;
  }

  float mrow[4], lrow[4];
  f32x4 oacc[4];
  f32x4 zz = {0.f, 0.f, 0.f, 0.f};
  #pragma unroll
  for (int r = 0; r < 4; ++r) { mrow[r] = -1e30f; lrow[r] = 0.f; }
  #pragma unroll
  for (int d = 0; d < 4; ++d) oacc[d] = zz;

  for (int kt = 0; kt < 32; ++kt) {
    const size_t kbase = qkvbase + 512 + (size_t)(kt * 64) * 1536;
    #pragma unroll
    for (int p = 0; p < 2; ++p) {
      const int row = srow + p * 32;
      *(bf16x8*)(Ks  + sw_off(row, scol * 2)) =
        *(const bf16x8*)(QKV + kbase + (size_t)row * 1536 + scol);
      *(bf16x8*)(VTs + sw_off(row, scol * 2)) =
        *(const bf16x8*)(VT + vtbase + (size_t)row * 2048 + kt * 64 + scol);
    }
    __syncthreads();

    // S = (Q/8) K^T
    f32x4 sf[4];
    __builtin_amdgcn_s_setprio(1);
    #pragma unroll
    for (int ct = 0; ct < 4; ++ct) {
      f32x4 s = zz;
      #pragma unroll
      for (int kk = 0; kk < 2; ++kk) {
        bf16x8 bb = *(const bf16x8*)(Ks + sw_off(ct*16 + lr, kk*64 + lg*16));
        s = __builtin_amdgcn_mfma_f32_16x16x32_bf16(aq[kk], bb, s, 0, 0, 0);
      }
      sf[ct] = s;
    }
    __builtin_amdgcn_s_setprio(0);

    // online softmax (rows r; 16-lane reduce over kv cols)
    #pragma unroll
    for (int r = 0; r < 4; ++r) {
      float tmax = fmaxf(fmaxf(sf[0][r], sf[1][r]), fmaxf(sf[2][r], sf[3][r]));
      #pragma unroll
      for (int off = 1; off < 16; off <<= 1) tmax = fmaxf(tmax, __shfl_xor(tmax, off));
      const float mnew = fmaxf(mrow[r], tmax);
      const float sc = __expf(mrow[r] - mnew);
      float psum = 0.f;
      #pragma unroll
      for (int ct = 0; ct < 4; ++ct) {
        float pv = __expf(sf[ct][r] - mnew);
        sf[ct][r] = pv;
        psum += pv;
      }
      #pragma unroll
      for (int off = 1; off < 16; off <<= 1) psum += __shfl_xor(psum, off);
      lrow[r] = lrow[r] * sc + psum;
      mrow[r] = mnew;
      #pragma unroll
      for (int d = 0; d < 4; ++d) oacc[d][r] *= sc;
    }

    // P -> LDS (per-wave buffer), element (q=lg*4+r, kv=ct*16+lr)
    #pragma unroll
    for (int ct = 0; ct < 4; ++ct)
      #pragma unroll
      for (int r = 0; r < 4; ++r)
        *(__bf16*)(Ps + w*2048 + sw_off(lg*4 + r, (ct*16 + lr) * 2)) = tobf(sf[ct][r]);

    // O += P @ V   (A = P rows q, B = VT rows d)
    __builtin_amdgcn_s_setprio(1);
    #pragma unroll
    for (int dt = 0; dt < 4; ++dt) {
      #pragma unroll
      for (int kk = 0; kk < 2; ++kk) {
        bf16x8 a  = *(const bf16x8*)(Ps  + w*2048 + sw_off(lr, kk*64 + lg*16));
        bf16x8 bb = *(const bf16x8*)(VTs + sw_off(dt*16 + lr, kk*64 + lg*16));
        oacc[dt] = __builtin_amdgcn_mfma_f32_16x16x32_bf16(a, bb, oacc[dt], 0, 0, 0);
      }
    }
    __builtin_amdgcn_s_setprio(0);
    __syncthreads();
  }

  float linv[4];
  #pragma unroll
  for (int r = 0; r < 4; ++r) linv[r] = 1.0f / lrow[r];
  #pragma unroll
  for (int dt = 0; dt < 4; ++dt)
    #pragma unroll
    for (int r = 0; r < 4; ++r) {
      const int row = q0 + w*16 + lg*4 + r;
      O[(size_t)(b * 2048 + row) * 512 + h*64 + dt*16 + lr] = tobf(oacc[dt][r] * linv[r]);
    }
}

// ---------------- LayerNorm over D=512; writes f32 and bf16 copies -----------
__global__ __launch_bounds__(256)
void ln_kernel(const float* __restrict__ in, const float* __restrict__ gw,
               const float* __restrict__ bw, float* __restrict__ outF,
               __bf16* __restrict__ outB)
{
  const int lane = threadIdx.x & 63;
  const size_t row = (size_t)blockIdx.x * 4 + (threadIdx.x >> 6);
  const float* p = in + row * 512 + lane * 8;
  float4 v0 = *(const float4*)p;
  float4 v1 = *(const float4*)(p + 4);
  float s = (v0.x + v0.y) + (v0.z + v0.w) + (v1.x + v1.y) + (v1.z + v1.w);
  float q = v0.x*v0.x + v0.y*v0.y + v0.z*v0.z + v0.w*v0.w
          + v1.x*v1.x + v1.y*v1.y + v1.z*v1.z + v1.w*v1.w;
  #pragma unroll
  for (int off = 1; off < 64; off <<= 1) { s += __shfl_xor(s, off); q += __shfl_xor(q, off); }
  const float mean = s * (1.0f / 512.0f);
  const float var  = q * (1.0f / 512.0f) - mean * mean;
  const float rs   = rsqrtf(var + 1e-6f);
  const float4 g0 = *(const float4*)(gw + lane * 8);
  const float4 g1 = *(const float4*)(gw + lane * 8 + 4);
  const float4 b0 = *(const float4*)(bw + lane * 8);
  const float4 b1 = *(const float4*)(bw + lane * 8 + 4);
  float4 o0, o1;
  o0.x = (v0.x - mean) * rs * g0.x + b0.x;
  o0.y = (v0.y - mean) * rs * g0.y + b0.y;
  o0.z = (v0.z - mean) * rs * g0.z + b0.z;
  o0.w = (v0.w - mean) * rs * g0.w + b0.w;
  o1.x = (v1.x - mean) * rs * g1.x + b1.x;
  o1.y = (v1.y - mean) * rs * g1.y + b1.y;
  o1.z = (v1.z - mean) * rs * g1.z + b1.z;
  o1.w = (v1.w - mean) * rs * g1.w + b1.w;
  *(float4*)(outF + row * 512 + lane * 8)     = o0;
  *(float4*)(outF + row * 512 + lane * 8 + 4) = o1;
  bf16x8 ob;
  ob[0]=tobf(o0.x); ob[1]=tobf(o0.y); ob[2]=tobf(o0.z); ob[3]=tobf(o0.w);
  ob[4]=tobf(o1.x); ob[5]=tobf(o1.y); ob[6]=tobf(o1.z); ob[7]=tobf(o1.w);
  *(bf16x8*)(outB + row * 512 + lane * 8) = ob;
}

// ---------------- launch ----------------
extern "C" void kernel_launch(void* const* d_in, const int* in_sizes, int n_in,
                              void* d_out, int out_size, void* d_ws, size_t ws_size,
                              hipStream_t stream)
{
  const float* x     = (const float*)d_in[0];
  const float* t_wq  = (const float*)d_in[1];
  const float* t_bq  = (const float*)d_in[2];
  const float* t_wk  = (const float*)d_in[3];
  const float* t_bk  = (const float*)d_in[4];
  const float* t_wv  = (const float*)d_in[5];
  const float* t_bv  = (const float*)d_in[6];
  const float* t_wo  = (const float*)d_in[7];
  const float* t_bo  = (const float*)d_in[8];
  const float* s_wq  = (const float*)d_in[9];
  const float* s_bq  = (const float*)d_in[10];
  const float* s_wk  = (const float*)d_in[11];
  const float* s_bk  = (const float*)d_in[12];
  const float* s_wv  = (const float*)d_in[13];
  const float* s_bv  = (const float*)d_in[14];
  const float* s_wo  = (const float*)d_in[15];
  const float* s_bo  = (const float*)d_in[16];
  const float* ln1_g = (const float*)d_in[17];
  const float* ln1_b = (const float*)d_in[18];
  const float* ln2_g = (const float*)d_in[19];
  const float* ln2_b = (const float*)d_in[20];
  const float* f_w1  = (const float*)d_in[21];
  const float* f_b1  = (const float*)d_in[22];
  const float* f_w2  = (const float*)d_in[23];
  const float* f_b2  = (const float*)d_in[24];

  char* ws = (char*)d_ws;
  size_t off = 0;
  auto alloc = [&](size_t bytes) -> void* {
    void* p = ws + off; off += (bytes + 255) & ~(size_t)255; return p;
  };

  __bf16* qkvb  = (__bf16*)alloc(8192ull * 1536 * 2);   // 25.2 MB
  __bf16* attnb = (__bf16*)alloc(8192ull * 512 * 2);    // 8.4 MB (contiguous after qkvb)
  __bf16* gelu_b = qkvb;                                // alias: spans qkvb+attnb (33.5 MB)
  __bf16* xb    = (__bf16*)alloc(8192ull * 512 * 2);
  __bf16* h_bf  = xb;                                   // alias: xb dead after QKV1
  __bf16* vtb   = (__bf16*)alloc(8192ull * 512 * 2);    // VT [B*H][64][2048]
  __bf16* wT_t  = (__bf16*)alloc(1536ull * 512 * 2);
  __bf16* wT_s  = (__bf16*)alloc(1536ull * 512 * 2);
  __bf16* woT_t = (__bf16*)alloc(512ull * 512 * 2);
  __bf16* woT_s = (__bf16*)alloc(512ull * 512 * 2);
  __bf16* w1T   = (__bf16*)alloc(2048ull * 512 * 2);
  __bf16* w2T   = (__bf16*)alloc(512ull * 2048 * 2);
  float* bcat_t = (float*)alloc(1536 * 4);
  float* bcat_s = (float*)alloc(1536 * 4);
  float* tmp_f  = (float*)alloc(8192ull * 512 * 4);
  float* h_f    = (float*)alloc(8192ull * 512 * 4);
  float* h2_f   = (float*)alloc(8192ull * 512 * 4);
  __bf16* h2_bf = (__bf16*)alloc(8192ull * 512 * 2);
  (void)in_sizes; (void)n_in; (void)out_size; (void)ws_size;

  // prepack
  cast_f32_bf16<<<2048, 256, 0, stream>>>(x, xb, 524288);
  transpose_cast<<<dim3(16,16), 256, 0, stream>>>(t_wq, wT_t,               512, 512);
  transpose_cast<<<dim3(16,16), 256, 0, stream>>>(t_wk, wT_t + 512*512,     512, 512);
  transpose_cast<<<dim3(16,16), 256, 0, stream>>>(t_wv, wT_t + 2*512*512,   512, 512);
  transpose_cast<<<dim3(16,16), 256, 0, stream>>>(s_wq, wT_s,               512, 512);
  transpose_cast<<<dim3(16,16), 256, 0, stream>>>(s_wk, wT_s + 512*512,     512, 512);
  transpose_cast<<<dim3(16,16), 256, 0, stream>>>(s_wv, wT_s + 2*512*512,   512, 512);
  transpose_cast<<<dim3(16,16), 256, 0, stream>>>(t_wo, woT_t,              512, 512);
  transpose_cast<<<dim3(16,16), 256, 0, stream>>>(s_wo, woT_s,              512, 512);
  transpose_cast<<<dim3(64,16), 256, 0, stream>>>(f_w1, w1T,                512, 2048);
  transpose_cast<<<dim3(16,64), 256, 0, stream>>>(f_w2, w2T,                2048, 512);
  concat3<<<6, 256, 0, stream>>>(t_bq, t_bk, t_bv, bcat_t, 512);
  concat3<<<6, 256, 0, stream>>>(s_bq, s_bk, s_bv, bcat_s, 512);

  // temporal attention
  gemm_bt<0><<<dim3(64,12), 256, 0, stream>>>(xb, wT_t, bcat_t, nullptr, qkvb, 8192, 1536, 512);
  transpose_v<<<dim3(32,32), 256, 0, stream>>>(qkvb, vtb);
  flash_attn<<<dim3(32,32), 256, 0, stream>>>(qkvb, vtb, attnb);
  gemm_bt<2><<<dim3(64,4),  256, 0, stream>>>(attnb, woT_t, t_bo, x, tmp_f, 8192, 512, 512);
  ln_kernel<<<2048, 256, 0, stream>>>(tmp_f, ln1_g, ln1_b, h_f, h_bf);

  // spatial attention
  gemm_bt<0><<<dim3(64,12), 256, 0, stream>>>(h_bf, wT_s, bcat_s, nullptr, qkvb, 8192, 1536, 512);
  transpose_v<<<dim3(32,32), 256, 0, stream>>>(qkvb, vtb);
  flash_attn<<<dim3(32,32), 256, 0, stream>>>(qkvb, vtb, attnb);
  gemm_bt<2><<<dim3(64,4),  256, 0, stream>>>(attnb, woT_s, s_bo, h_f, tmp_f, 8192, 512, 512);
  ln_kernel<<<2048, 256, 0, stream>>>(tmp_f, ln2_g, ln2_b, h2_f, h2_bf);

  // FFN
  gemm_bt<1><<<dim3(64,16), 256, 0, stream>>>(h2_bf, w1T, f_b1, nullptr, gelu_b, 8192, 2048, 512);
  gemm_bt<2><<<dim3(64,4),  256, 0, stream>>>(gelu_b, w2T, f_b2, h2_f, (float*)d_out, 8192, 512, 2048);
}

// Round 7
// 488.983 us; speedup vs baseline: 1.1920x; 1.0938x over previous
//
#include <hip/hip_runtime.h>

typedef __bf16 bf16x8 __attribute__((ext_vector_type(8)));
typedef float  f32x4  __attribute__((ext_vector_type(4)));

#define DEVI static __device__ __forceinline__

DEVI __bf16 tobf(float f) { return static_cast<__bf16>(f); }

DEVI unsigned pack2bf(float a, float b) {
  union { __bf16 h[2]; unsigned u; } c;
  c.h[0] = tobf(a); c.h[1] = tobf(b);
  return c.u;
}

// ---------------- cast fp32 -> bf16 (8 elems / thread) ----------------
__global__ __launch_bounds__(256) void cast_f32_bf16(
    const float* __restrict__ in, __bf16* __restrict__ out, int n8)
{
  int i = blockIdx.x * 256 + threadIdx.x;
  if (i >= n8) return;
  const float4* p = (const float4*)in + (size_t)i * 2;
  float4 a = p[0], b = p[1];
  bf16x8 o;
  o[0]=tobf(a.x); o[1]=tobf(a.y); o[2]=tobf(a.z); o[3]=tobf(a.w);
  o[4]=tobf(b.x); o[5]=tobf(b.y); o[6]=tobf(b.z); o[7]=tobf(b.w);
  ((bf16x8*)out)[i] = o;
}

// ---------------- transpose + cast: W[R,C] f32 -> Wt[C,R] bf16 ----------------
__global__ __launch_bounds__(256) void transpose_cast(
    const float* __restrict__ W, __bf16* __restrict__ Wt, int R, int C)
{
  __shared__ float tile[32][33];
  const int tx = threadIdx.x & 31;
  const int ty = threadIdx.x >> 5;              // 0..7
  const int c0 = blockIdx.x * 32, r0 = blockIdx.y * 32;
  #pragma unroll
  for (int i = 0; i < 4; ++i)
    tile[ty + i*8][tx] = W[(size_t)(r0 + ty + i*8) * C + c0 + tx];
  __syncthreads();
  #pragma unroll
  for (int i = 0; i < 4; ++i)
    Wt[(size_t)(c0 + ty + i*8) * R + r0 + tx] = tobf(tile[tx][ty + i*8]);
}

// ---------------- concat 3 bias vectors of length n ----------------
__global__ __launch_bounds__(256) void concat3(
    const float* __restrict__ a, const float* __restrict__ b,
    const float* __restrict__ c, float* __restrict__ out, int n)
{
  int i = blockIdx.x * 256 + threadIdx.x;
  if (i < n) out[i] = a[i];
  else if (i < 2*n) out[i] = b[i - n];
  else if (i < 3*n) out[i] = c[i - 2*n];
}

// ------- transpose V slice of QKV into VT[b][h][d=64][s=2048] bf16 -------
// grid: (S/64, B*H); block 256.
__global__ __launch_bounds__(256)
void transpose_v(const __bf16* __restrict__ QKV, __bf16* __restrict__ VT)
{
  __shared__ __bf16 t[64][72];
  const int tid = threadIdx.x;
  const int bh = blockIdx.y;
  const int b = bh >> 3, h = bh & 7;
  const int s0 = blockIdx.x * 64;
  const int srow = tid >> 3, scol = (tid & 7) * 8;
  #pragma unroll
  for (int p = 0; p < 2; ++p) {
    const int row = srow + p * 32;
    *(bf16x8*)&t[row][scol] =
      *(const bf16x8*)(QKV + (size_t)(b * 2048 + s0 + row) * 1536 + 1024 + h * 64 + scol);
  }
  __syncthreads();
  #pragma unroll
  for (int p = 0; p < 2; ++p) {
    const int d = srow + p * 32;
    bf16x8 v;
    #pragma unroll
    for (int e = 0; e < 8; ++e) v[e] = t[scol + e][d];
    *(bf16x8*)(VT + ((size_t)bh * 64 + d) * 2048 + s0 + scol) = v;
  }
}

// ---------------- BT-GEMM: C[M,N] = A[M,K] @ Bt[N,K]^T (+bias, epilogue) ------
// EPI 0: bias -> bf16 out     EPI 1: bias + exact GELU -> bf16 out
// EPI 2: bias + resid(f32) -> f32 out
template<int EPI>
__global__ __launch_bounds__(256)
void gemm_bt(const __bf16* __restrict__ A, const __bf16* __restrict__ Bt,
             const float* __restrict__ bias, const float* __restrict__ resid,
             void* __restrict__ out, int M, int N, int K)
{
  __shared__ __bf16 As[128][72];
  __shared__ __bf16 Bs[128][72];
  const int tid  = threadIdx.x;
  const int lane = tid & 63;
  const int wave = tid >> 6;
  const int wm = wave >> 1, wn = wave & 1;
  const int m0 = blockIdx.x * 128, n0 = blockIdx.y * 128;
  const int lr = lane & 15, lg = lane >> 4;
  const int srow = tid >> 3, scol = (tid & 7) * 8;

  f32x4 acc[4][4];
  f32x4 zz = {0.f, 0.f, 0.f, 0.f};
  #pragma unroll
  for (int i = 0; i < 4; ++i)
    #pragma unroll
    for (int j = 0; j < 4; ++j) acc[i][j] = zz;

  for (int k0 = 0; k0 < K; k0 += 64) {
    #pragma unroll
    for (int p = 0; p < 4; ++p) {
      const int row = p * 32 + srow;
      *(bf16x8*)&As[row][scol] = *(const bf16x8*)(A  + (size_t)(m0 + row) * K + k0 + scol);
      *(bf16x8*)&Bs[row][scol] = *(const bf16x8*)(Bt + (size_t)(n0 + row) * K + k0 + scol);
    }
    __syncthreads();
    #pragma unroll
    for (int kk = 0; kk < 2; ++kk) {
      bf16x8 af[4], bfr[4];
      #pragma unroll
      for (int i = 0; i < 4; ++i) af[i]  = *(const bf16x8*)&As[wm*64 + i*16 + lr][kk*32 + lg*8];
      #pragma unroll
      for (int j = 0; j < 4; ++j) bfr[j] = *(const bf16x8*)&Bs[wn*64 + j*16 + lr][kk*32 + lg*8];
      #pragma unroll
      for (int i = 0; i < 4; ++i)
        #pragma unroll
        for (int j = 0; j < 4; ++j)
          acc[i][j] = __builtin_amdgcn_mfma_f32_16x16x32_bf16(af[i], bfr[j], acc[i][j], 0, 0, 0);
    }
    __syncthreads();
  }

  const int orow = m0 + wm * 64;
  const int ocol = n0 + wn * 64;
  #pragma unroll
  for (int j = 0; j < 4; ++j) {
    const int col = ocol + j*16 + lr;
    const float bv = bias[col];
    #pragma unroll
    for (int i = 0; i < 4; ++i) {
      #pragma unroll
      for (int r = 0; r < 4; ++r) {
        const int row = orow + i*16 + lg*4 + r;
        const size_t o = (size_t)row * N + col;
        float v = acc[i][j][r] + bv;
        if (EPI == 0) {
          ((__bf16*)out)[o] = tobf(v);
        } else if (EPI == 1) {
          float g = 0.5f * v * (1.0f + erff(v * 0.7071067811865476f));
          ((__bf16*)out)[o] = tobf(g);
        } else {
          ((float*)out)[o] = v + resid[o];
        }
      }
    }
  }
}

// ---------------- flash attention v3 ----------------
// Swapped QK^T (mfma(K,Q)) => lane owns P[q=lane&15][kv in own lg slots];
// softmax + P->bf16 fully in registers (no P LDS round trip).
// QKV: [B*S, 1536] bf16 (Q|K|V each 512 = 8 heads x 64).
// VT:  [B*H][64][2048] bf16 (V transposed per head).
// O:   [B*S, 512] bf16.
// grid: (S/64, B*H); block 256 (4 waves x 16 q-rows each).
// LDS swizzle: byte(row, colByte) = row*128 + (colByte ^ ((row&7)<<4))
DEVI int sw_off(int row, int colByte) {
  return row * 128 + (colByte ^ ((row & 7) << 4));
}

__global__ __launch_bounds__(256)
void flash_attn(const __bf16* __restrict__ QKV, const __bf16* __restrict__ VT,
                __bf16* __restrict__ O)
{
  __shared__ __align__(16) char Ks [64 * 128];
  __shared__ __align__(16) char VTs[64 * 128];

  const int tid  = threadIdx.x;
  const int lane = tid & 63;
  const int w    = tid >> 6;
  const int lr = lane & 15, lg = lane >> 4;
  const int bh = blockIdx.y;
  const int b = bh >> 3, h = bh & 7;
  const int q0 = blockIdx.x * 64;
  const size_t qkvbase = (size_t)b * 2048 * 1536 + h * 64;
  const size_t vtbase  = (size_t)bh * 64 * 2048;
  const int srow = tid >> 3, scol = (tid & 7) * 8;

  // Q fragment (B-operand: lane.lr = q row), pre-scaled by 1/sqrt(64)=0.125
  bf16x8 aq[2];
  #pragma unroll
  for (int kk = 0; kk < 2; ++kk) {
    bf16x8 t = *(const bf16x8*)(QKV + qkvbase +
                 (size_t)(q0 + w*16 + lr) * 1536 + kk*32 + lg*8);
    #pragma unroll
    for (int e = 0; e < 8; ++e) t[e] = tobf(0.125f * (float)t[e]);
    aq[kk] = t;
  }

  float mrow = -1e30f, lrow = 0.f;   // per lane, for q = w*16 + lr
  f32x4 oacc[4];
  f32x4 zz = {0.f, 0.f, 0.f, 0.f};
  #pragma unroll
  for (int d = 0; d < 4; ++d) oacc[d] = zz;

  const int srcA = lr + ((lg & 1) << 5);   // partner lanes for P A-frag build
  const int srcB = srcA + 16;
  const bool sel = ((lg >> 1) & 1) != 0;

  for (int kt = 0; kt < 32; ++kt) {
    const size_t kbase = qkvbase + 512 + (size_t)(kt * 64) * 1536;
    #pragma unroll
    for (int p = 0; p < 2; ++p) {
      const int row = srow + p * 32;
      *(bf16x8*)(Ks  + sw_off(row, scol * 2)) =
        *(const bf16x8*)(QKV + kbase + (size_t)row * 1536 + scol);
      *(bf16x8*)(VTs + sw_off(row, scol * 2)) =
        *(const bf16x8*)(VT + vtbase + (size_t)row * 2048 + kt * 64 + scol);
    }
    __syncthreads();

    // S^T = K (Q/8)^T : lane holds S[kv = ct*16 + lg*4 + r][q = lr]
    f32x4 sf[4];
    __builtin_amdgcn_s_setprio(1);
    #pragma unroll
    for (int ct = 0; ct < 4; ++ct) {
      f32x4 s = zz;
      #pragma unroll
      for (int kk = 0; kk < 2; ++kk) {
        bf16x8 kf = *(const bf16x8*)(Ks + sw_off(ct*16 + lr, kk*64 + lg*16));
        s = __builtin_amdgcn_mfma_f32_16x16x32_bf16(kf, aq[kk], s, 0, 0, 0);
      }
      sf[ct] = s;
    }
    __builtin_amdgcn_s_setprio(0);

    // online softmax: each lane owns 16 kv values for its q=lr; full row across
    // lanes {lr, lr+16, lr+32, lr+48}
    float tmax = sf[0][0];
    #pragma unroll
    for (int ct = 0; ct < 4; ++ct)
      #pragma unroll
      for (int r = 0; r < 4; ++r) tmax = fmaxf(tmax, sf[ct][r]);
    tmax = fmaxf(tmax, __shfl_xor(tmax, 16));
    tmax = fmaxf(tmax, __shfl_xor(tmax, 32));
    const float mnew = fmaxf(mrow, tmax);
    const float sc = __expf(mrow - mnew);
    float psum = 0.f;
    #pragma unroll
    for (int ct = 0; ct < 4; ++ct)
      #pragma unroll
      for (int r = 0; r < 4; ++r) {
        float pv = __expf(sf[ct][r] - mnew);
        sf[ct][r] = pv;
        psum += pv;
      }
    psum += __shfl_xor(psum, 16);
    psum += __shfl_xor(psum, 32);
    lrow = lrow * sc + psum;
    mrow = mnew;

    // rescale O (rows q' = lg*4 + r): pull sc from lane q'
    float scq[4];
    #pragma unroll
    for (int r = 0; r < 4; ++r) scq[r] = __shfl(sc, lg*4 + r);
    #pragma unroll
    for (int dt = 0; dt < 4; ++dt)
      #pragma unroll
      for (int r = 0; r < 4; ++r) oacc[dt][r] *= scq[r];

    // pack P to bf16 pairs: pk0[ct]=(r0,r1), pk1[ct]=(r2,r3)
    unsigned pk0[4], pk1[4];
    #pragma unroll
    for (int ct = 0; ct < 4; ++ct) {
      pk0[ct] = pack2bf(sf[ct][0], sf[ct][1]);
      pk1[ct] = pack2bf(sf[ct][2], sf[ct][3]);
    }

    // build PV A-fragments in-register:
    // elem e of frag kk = P[q=lr][kv=kk*32+lg*8+e], owner lane = lr+32*(lg&1)+16*(e>>2),
    // owner regs pk*[kk*2 + (lg>>1)]
    bf16x8 pa[2];
    #pragma unroll
    for (int kk = 0; kk < 2; ++kk) {
      const int c0 = kk*2, c1 = kk*2 + 1;
      unsigned a0 = __shfl(pk0[c0], srcA), a1 = __shfl(pk1[c0], srcA);
      unsigned a2 = __shfl(pk0[c0], srcB), a3 = __shfl(pk1[c0], srcB);
      unsigned b0 = __shfl(pk0[c1], srcA), b1 = __shfl(pk1[c1], srcA);
      unsigned b2 = __shfl(pk0[c1], srcB), b3 = __shfl(pk1[c1], srcB);
      union { unsigned u[4]; bf16x8 v; } cu;
      cu.u[0] = sel ? b0 : a0;
      cu.u[1] = sel ? b1 : a1;
      cu.u[2] = sel ? b2 : a2;
      cu.u[3] = sel ? b3 : a3;
      pa[kk] = cu.v;
    }

    // O += P @ V   (A = P rows q, B = VT rows d)
    __builtin_amdgcn_s_setprio(1);
    #pragma unroll
    for (int dt = 0; dt < 4; ++dt) {
      #pragma unroll
      for (int kk = 0; kk < 2; ++kk) {
        bf16x8 bb = *(const bf16x8*)(VTs + sw_off(dt*16 + lr, kk*64 + lg*16));
        oacc[dt] = __builtin_amdgcn_mfma_f32_16x16x32_bf16(pa[kk], bb, oacc[dt], 0, 0, 0);
      }
    }
    __builtin_amdgcn_s_setprio(0);
    __syncthreads();
  }

  // normalize: pull l for row q' = lg*4 + r from lane q'
  float linv[4];
  #pragma unroll
  for (int r = 0; r < 4; ++r) {
    float lq = __shfl(lrow, lg*4 + r);
    linv[r] = 1.0f / lq;
  }
  #pragma unroll
  for (int dt = 0; dt < 4; ++dt)
    #pragma unroll
    for (int r = 0; r < 4; ++r) {
      const int row = q0 + w*16 + lg*4 + r;
      O[(size_t)(b * 2048 + row) * 512 + h*64 + dt*16 + lr] = tobf(oacc[dt][r] * linv[r]);
    }
}

// ---------------- LayerNorm over D=512; writes f32 and bf16 copies -----------
__global__ __launch_bounds__(256)
void ln_kernel(const float* __restrict__ in, const float* __restrict__ gw,
               const float* __restrict__ bw, float* __restrict__ outF,
               __bf16* __restrict__ outB)
{
  const int lane = threadIdx.x & 63;
  const size_t row = (size_t)blockIdx.x * 4 + (threadIdx.x >> 6);
  const float* p = in + row * 512 + lane * 8;
  float4 v0 = *(const float4*)p;
  float4 v1 = *(const float4*)(p + 4);
  float s = (v0.x + v0.y) + (v0.z + v0.w) + (v1.x + v1.y) + (v1.z + v1.w);
  float q = v0.x*v0.x + v0.y*v0.y + v0.z*v0.z + v0.w*v0.w
          + v1.x*v1.x + v1.y*v1.y + v1.z*v1.z + v1.w*v1.w;
  #pragma unroll
  for (int off = 1; off < 64; off <<= 1) { s += __shfl_xor(s, off); q += __shfl_xor(q, off); }
  const float mean = s * (1.0f / 512.0f);
  const float var  = q * (1.0f / 512.0f) - mean * mean;
  const float rs   = rsqrtf(var + 1e-6f);
  const float4 g0 = *(const float4*)(gw + lane * 8);
  const float4 g1 = *(const float4*)(gw + lane * 8 + 4);
  const float4 b0 = *(const float4*)(bw + lane * 8);
  const float4 b1 = *(const float4*)(bw + lane * 8 + 4);
  float4 o0, o1;
  o0.x = (v0.x - mean) * rs * g0.x + b0.x;
  o0.y = (v0.y - mean) * rs * g0.y + b0.y;
  o0.z = (v0.z - mean) * rs * g0.z + b0.z;
  o0.w = (v0.w - mean) * rs * g0.w + b0.w;
  o1.x = (v1.x - mean) * rs * g1.x + b1.x;
  o1.y = (v1.y - mean) * rs * g1.y + b1.y;
  o1.z = (v1.z - mean) * rs * g1.z + b1.z;
  o1.w = (v1.w - mean) * rs * g1.w + b1.w;
  *(float4*)(outF + row * 512 + lane * 8)     = o0;
  *(float4*)(outF + row * 512 + lane * 8 + 4) = o1;
  bf16x8 ob;
  ob[0]=tobf(o0.x); ob[1]=tobf(o0.y); ob[2]=tobf(o0.z); ob[3]=tobf(o0.w);
  ob[4]=tobf(o1.x); ob[5]=tobf(o1.y); ob[6]=tobf(o1.z); ob[7]=tobf(o1.w);
  *(bf16x8*)(outB + row * 512 + lane * 8) = ob;
}

// ---------------- launch ----------------
extern "C" void kernel_launch(void* const* d_in, const int* in_sizes, int n_in,
                              void* d_out, int out_size, void* d_ws, size_t ws_size,
                              hipStream_t stream)
{
  const float* x     = (const float*)d_in[0];
  const float* t_wq  = (const float*)d_in[1];
  const float* t_bq  = (const float*)d_in[2];
  const float* t_wk  = (const float*)d_in[3];
  const float* t_bk  = (const float*)d_in[4];
  const float* t_wv  = (const float*)d_in[5];
  const float* t_bv  = (const float*)d_in[6];
  const float* t_wo  = (const float*)d_in[7];
  const float* t_bo  = (const float*)d_in[8];
  const float* s_wq  = (const float*)d_in[9];
  const float* s_bq  = (const float*)d_in[10];
  const float* s_wk  = (const float*)d_in[11];
  const float* s_bk  = (const float*)d_in[12];
  const float* s_wv  = (const float*)d_in[13];
  const float* s_bv  = (const float*)d_in[14];
  const float* s_wo  = (const float*)d_in[15];
  const float* s_bo  = (const float*)d_in[16];
  const float* ln1_g = (const float*)d_in[17];
  const float* ln1_b = (const float*)d_in[18];
  const float* ln2_g = (const float*)d_in[19];
  const float* ln2_b = (const float*)d_in[20];
  const float* f_w1  = (const float*)d_in[21];
  const float* f_b1  = (const float*)d_in[22];
  const float* f_w2  = (const float*)d_in[23];
  const float* f_b2  = (const float*)d_in[24];

  char* ws = (char*)d_ws;
  size_t off = 0;
  auto alloc = [&](size_t bytes) -> void* {
    void* p = ws + off; off += (bytes + 255) & ~(size_t)255; return p;
  };

  __bf16* qkvb  = (__bf16*)alloc(8192ull * 1536 * 2);   // 25.2 MB
  __bf16* attnb = (__bf16*)alloc(8192ull * 512 * 2);    // 8.4 MB (contiguous after qkvb)
  __bf16* gelu_b = qkvb;                                // alias: spans qkvb+attnb (33.5 MB)
  __bf16* xb    = (__bf16*)alloc(8192ull * 512 * 2);
  __bf16* h_bf  = xb;                                   // alias: xb dead after QKV1
  __bf16* vtb   = (__bf16*)alloc(8192ull * 512 * 2);    // VT [B*H][64][2048]
  __bf16* wT_t  = (__bf16*)alloc(1536ull * 512 * 2);
  __bf16* wT_s  = (__bf16*)alloc(1536ull * 512 * 2);
  __bf16* woT_t = (__bf16*)alloc(512ull * 512 * 2);
  __bf16* woT_s = (__bf16*)alloc(512ull * 512 * 2);
  __bf16* w1T   = (__bf16*)alloc(2048ull * 512 * 2);
  __bf16* w2T   = (__bf16*)alloc(512ull * 2048 * 2);
  float* bcat_t = (float*)alloc(1536 * 4);
  float* bcat_s = (float*)alloc(1536 * 4);
  float* tmp_f  = (float*)alloc(8192ull * 512 * 4);
  float* h_f    = (float*)alloc(8192ull * 512 * 4);
  float* h2_f   = (float*)alloc(8192ull * 512 * 4);
  __bf16* h2_bf = (__bf16*)alloc(8192ull * 512 * 2);
  (void)in_sizes; (void)n_in; (void)out_size; (void)ws_size;

  // prepack
  cast_f32_bf16<<<2048, 256, 0, stream>>>(x, xb, 524288);
  transpose_cast<<<dim3(16,16), 256, 0, stream>>>(t_wq, wT_t,               512, 512);
  transpose_cast<<<dim3(16,16), 256, 0, stream>>>(t_wk, wT_t + 512*512,     512, 512);
  transpose_cast<<<dim3(16,16), 256, 0, stream>>>(t_wv, wT_t + 2*512*512,   512, 512);
  transpose_cast<<<dim3(16,16), 256, 0, stream>>>(s_wq, wT_s,               512, 512);
  transpose_cast<<<dim3(16,16), 256, 0, stream>>>(s_wk, wT_s + 512*512,     512, 512);
  transpose_cast<<<dim3(16,16), 256, 0, stream>>>(s_wv, wT_s + 2*512*512,   512, 512);
  transpose_cast<<<dim3(16,16), 256, 0, stream>>>(t_wo, woT_t,              512, 512);
  transpose_cast<<<dim3(16,16), 256, 0, stream>>>(s_wo, woT_s,              512, 512);
  transpose_cast<<<dim3(64,16), 256, 0, stream>>>(f_w1, w1T,                512, 2048);
  transpose_cast<<<dim3(16,64), 256, 0, stream>>>(f_w2, w2T,                2048, 512);
  concat3<<<6, 256, 0, stream>>>(t_bq, t_bk, t_bv, bcat_t, 512);
  concat3<<<6, 256, 0, stream>>>(s_bq, s_bk, s_bv, bcat_s, 512);

  // temporal attention
  gemm_bt<0><<<dim3(64,12), 256, 0, stream>>>(xb, wT_t, bcat_t, nullptr, qkvb, 8192, 1536, 512);
  transpose_v<<<dim3(32,32), 256, 0, stream>>>(qkvb, vtb);
  flash_attn<<<dim3(32,32), 256, 0, stream>>>(qkvb, vtb, attnb);
  gemm_bt<2><<<dim3(64,4),  256, 0, stream>>>(attnb, woT_t, t_bo, x, tmp_f, 8192, 512, 512);
  ln_kernel<<<2048, 256, 0, stream>>>(tmp_f, ln1_g, ln1_b, h_f, h_bf);

  // spatial attention
  gemm_bt<0><<<dim3(64,12), 256, 0, stream>>>(h_bf, wT_s, bcat_s, nullptr, qkvb, 8192, 1536, 512);
  transpose_v<<<dim3(32,32), 256, 0, stream>>>(qkvb, vtb);
  flash_attn<<<dim3(32,32), 256, 0, stream>>>(qkvb, vtb, attnb);
  gemm_bt<2><<<dim3(64,4),  256, 0, stream>>>(attnb, woT_s, s_bo, h_f, tmp_f, 8192, 512, 512);
  ln_kernel<<<2048, 256, 0, stream>>>(tmp_f, ln2_g, ln2_b, h2_f, h2_bf);

  // FFN
  gemm_bt<1><<<dim3(64,16), 256, 0, stream>>>(h2_bf, w1T, f_b1, nullptr, gelu_b, 8192, 2048, 512);
  gemm_bt<2><<<dim3(64,4),  256, 0, stream>>>(gelu_b, w2T, f_b2, h2_f, (float*)d_out, 8192, 512, 2048);
}